// Round 14
// baseline (167.426 us; speedup 1.0000x reference)
//
#include <hip/hip_runtime.h>
#include <math.h>

#define NTOK 4096
#define INDIM 128
#define PD 16384      // D = OUT*IN
#define NPAT 8
#define KSEL 1638     // int(16384*0.1)
#define HEDGE_ULP 8
#define HEDGE_CUT 0.066f
#define LISTCAP 1024

typedef float nt4 __attribute__((ext_vector_type(4)));  // native vec for NT stores

#define KEY32(f) (__float_as_uint(f) & 0x7fffffffu)
#define HEDGED(key, val, T) \
    ((((key) >= (T) ? (key) - (T) : (T) - (key)) <= (unsigned int)HEDGE_ULP) \
     && (fabsf(val) < HEDGE_CUT))

// ---------------------------------------------------------------------------
// Kernel 0: logits + softmax + sigmoid per token (validated arithmetic).
// ---------------------------------------------------------------------------
__global__ __launch_bounds__(256) void logits_kernel(
    const float* __restrict__ x,
    const float* __restrict__ Wp,
    const float* __restrict__ bp,
    const float* __restrict__ Wi,
    const float* __restrict__ bi,
    float* __restrict__ wsm)
{
    const int tid = threadIdx.x;
    const int lane = tid & 63;
    const int wv = tid >> 6;
    const int token = blockIdx.x * 4 + wv;

    float acc = 0.0f;
    if (lane < 9) {
        const float* xrow = x + (size_t)token * INDIM;
        if (lane < 8) {
            for (int l = 0; l < INDIM; ++l)
                acc = __fmaf_rn(xrow[l], Wp[l * NPAT + lane], acc);
            acc = __fadd_rn(acc, bp[lane]);
        } else {
            for (int l = 0; l < INDIM; ++l)
                acc = __fmaf_rn(xrow[l], Wi[l], acc);
            acc = __fadd_rn(acc, bi[0]);
        }
    }
    float d[9];
#pragma unroll
    for (int c = 0; c < 9; ++c) d[c] = __shfl(acc, c, 64);

    if (lane == 0) {
        float m = d[0];
#pragma unroll
        for (int c = 1; c < 8; ++c) m = fmaxf(m, d[c]);
        float ee[8];
#pragma unroll
        for (int c = 0; c < 8; ++c)
            ee[c] = (float)exp((double)__fsub_rn(d[c], m));
        const float ssum = __fadd_rn(
            __fadd_rn(__fadd_rn(ee[0], ee[1]), __fadd_rn(ee[2], ee[3])),
            __fadd_rn(__fadd_rn(ee[4], ee[5]), __fadd_rn(ee[6], ee[7])));
        double ent = 0.0;
        float* wrow = wsm + (size_t)token * 10;
#pragma unroll
        for (int c = 0; c < 8; ++c) {
            const float p = __fdiv_rn(ee[c], ssum);
            wrow[c] = p;
            ent -= (double)p * log((double)p + 1e-8);
        }
        const float z = d[8];
        const float einv = (float)exp(-(double)z);
        const float it = __fdiv_rn(1.0f, __fadd_rn(1.0f, einv));
        wrow[8] = it;
        wrow[9] = (float)ent;
    }
}

// ---------------------------------------------------------------------------
// Kernel 1: one 1024-thread block per TWO tokens — each pat float4 feeds both
// tokens' validated FMA chains (halves pat L2 traffic to 1.05 GB). Token A's
// 16 values/thread in REGISTERS, token B's in LDS (64 KB). VGPR ~80 <= 128.
//  select : R8's two-half radix (half = tid>>9): p0 11-bit fused into mixture,
//           p1 10-bit (regs + one LDS scan, survivor lists), p2 6-bit and
//           p3 4-bit from lists (wave 0/8 scans); ovf -> exact rescan.
//  write  : hedged nontemporal stores.
// ---------------------------------------------------------------------------
__global__ __launch_bounds__(1024) void flow_kernel(
    const float* __restrict__ pat,
    const float* __restrict__ wsm,
    float* __restrict__ out)
{
    __shared__ float4 vldsB[4096];           // 64 KB: token B's values
    __shared__ int hist[2][2048];            // 16 KB: [token][bin], reused per pass
    __shared__ unsigned int listA[LISTCAP];  // 4 KB
    __shared__ unsigned int listB[LISTCAP];  // 4 KB
    __shared__ int listCnt[2];
    __shared__ int waveTot[2][8];
    __shared__ int bc_d[2], bc_kk[2], bc_eq[2];
    __shared__ int ovf;
    __shared__ int baseCnt;

    const int tid  = threadIdx.x;
    const int wv   = tid >> 6;
    const int lane = tid & 63;
    const int half = tid >> 9;               // scan role: 0=token A, 1=token B
    const int L    = tid & 511;              // lane within half
    const int lwv  = (tid >> 6) & 7;         // wave within half
    const int tokA = blockIdx.x * 2;
    const int tokB = tokA + 1;

    // ---- zero histograms & flags; must complete before fused atomics ----
    {
        int* hp = &hist[0][0];
        hp[tid] = 0; hp[tid + 1024] = 0; hp[tid + 2048] = 0; hp[tid + 3072] = 0;
    }
    if (tid == 0) { ovf = 0; listCnt[0] = 0; listCnt[1] = 0; }
    __syncthreads();  // B0

    const float* wrA = wsm + (size_t)tokA * 10;
    const float* wrB = wsm + (size_t)tokB * 10;
    float pwA[8], pwB[8];
#pragma unroll
    for (int c = 0; c < 8; ++c) { pwA[c] = wrA[c]; pwB[c] = wrB[c]; }
    const float intenA = wrA[8];
    const float intenB = wrB[8];

    // ---- mixture (validated per-element) + fused p0 hist (bits 30..20) ----
    float vrA[16];                           // token A's values: registers
#pragma unroll
    for (int i = 0; i < 4; ++i) {
        const int e = i * 4096 + tid * 4;
        float4 ap = *(const float4*)(pat + e);
        float rA0 = __fmul_rn(pwA[0], ap.x), rB0 = __fmul_rn(pwB[0], ap.x);
        float rA1 = __fmul_rn(pwA[0], ap.y), rB1 = __fmul_rn(pwB[0], ap.y);
        float rA2 = __fmul_rn(pwA[0], ap.z), rB2 = __fmul_rn(pwB[0], ap.z);
        float rA3 = __fmul_rn(pwA[0], ap.w), rB3 = __fmul_rn(pwB[0], ap.w);
#pragma unroll
        for (int p = 1; p < NPAT; ++p) {
            ap = *(const float4*)(pat + (size_t)p * PD + e);
            rA0 = __fadd_rn(rA0, __fmul_rn(pwA[p], ap.x));
            rB0 = __fadd_rn(rB0, __fmul_rn(pwB[p], ap.x));
            rA1 = __fadd_rn(rA1, __fmul_rn(pwA[p], ap.y));
            rB1 = __fadd_rn(rB1, __fmul_rn(pwB[p], ap.y));
            rA2 = __fadd_rn(rA2, __fmul_rn(pwA[p], ap.z));
            rB2 = __fadd_rn(rB2, __fmul_rn(pwB[p], ap.z));
            rA3 = __fadd_rn(rA3, __fmul_rn(pwA[p], ap.w));
            rB3 = __fadd_rn(rB3, __fmul_rn(pwB[p], ap.w));
        }
        vrA[i * 4 + 0] = __fmul_rn(rA0, intenA);
        vrA[i * 4 + 1] = __fmul_rn(rA1, intenA);
        vrA[i * 4 + 2] = __fmul_rn(rA2, intenA);
        vrA[i * 4 + 3] = __fmul_rn(rA3, intenA);
        float4 ob;
        ob.x = __fmul_rn(rB0, intenB);
        ob.y = __fmul_rn(rB1, intenB);
        ob.z = __fmul_rn(rB2, intenB);
        ob.w = __fmul_rn(rB3, intenB);
        vldsB[i * 1024 + tid] = ob;
        atomicAdd(&hist[0][KEY32(vrA[i * 4 + 0]) >> 20], 1);
        atomicAdd(&hist[0][KEY32(vrA[i * 4 + 1]) >> 20], 1);
        atomicAdd(&hist[0][KEY32(vrA[i * 4 + 2]) >> 20], 1);
        atomicAdd(&hist[0][KEY32(vrA[i * 4 + 3]) >> 20], 1);
        atomicAdd(&hist[1][KEY32(ob.x) >> 20], 1);
        atomicAdd(&hist[1][KEY32(ob.y) >> 20], 1);
        atomicAdd(&hist[1][KEY32(ob.z) >> 20], 1);
        atomicAdd(&hist[1][KEY32(ob.w) >> 20], 1);
    }
    __syncthreads();  // B1: values ready, p0 hist complete

    // ---- p0 scan: per half, L owns 4 bins -> d0 (bits 30..20) ----
    {
        int c4[4];
#pragma unroll
        for (int k = 0; k < 4; ++k) c4[k] = hist[half][L * 4 + k];
        const int pt = c4[0] + c4[1] + c4[2] + c4[3];
        int s = pt;
#pragma unroll
        for (int off = 1; off < 64; off <<= 1) {
            const int t = __shfl_down(s, off, 64);
            if (lane + off < 64) s += t;
        }
        if (lane == 0) waveTot[half][lwv] = s;
        __syncthreads();  // B2
        int U = s - pt;
#pragma unroll
        for (int w = 0; w < 8; ++w) if (w > lwv) U += waveTot[half][w];
        const int kk0 = KSEL;
        int suf = 0;
#pragma unroll
        for (int k = 3; k >= 0; --k) {
            suf += c4[k];
            const int incl = U + suf;
            const int gg = incl - c4[k];
            if (gg < kk0 && kk0 <= incl) { bc_d[half] = L * 4 + k; bc_kk[half] = kk0 - gg; }
        }
        __syncthreads();  // B3
    }
    const unsigned int d0A = (unsigned int)bc_d[0];
    const unsigned int d0B = (unsigned int)bc_d[1];
    int kkA = bc_kk[0], kkB = bc_kk[1];
    hist[0][tid & 1023] = 0; hist[1][tid & 1023] = 0;   // rezero bins 0..1023 (x2 writers, benign)
    __syncthreads();  // B4

    // ---- p1: regs(A) + LDS scan(B); hist bits 19..10; push survivors ----
#pragma unroll
    for (int q = 0; q < 16; ++q) {
        const unsigned int key = KEY32(vrA[q]);
        if ((key >> 20) == d0A) {
            atomicAdd(&hist[0][(key >> 10) & 1023], 1);
            const int pos = atomicAdd(&listCnt[0], 1);
            if (pos < LISTCAP) listA[pos] = key; else ovf = 1;
        }
    }
#pragma unroll
    for (int i = 0; i < 4; ++i) {
        const float4 vv = vldsB[i * 1024 + tid];
        const float vj[4] = {vv.x, vv.y, vv.z, vv.w};
#pragma unroll
        for (int j = 0; j < 4; ++j) {
            const unsigned int key = KEY32(vj[j]);
            if ((key >> 20) == d0B) {
                atomicAdd(&hist[1][(key >> 10) & 1023], 1);
                const int pos = atomicAdd(&listCnt[1], 1);
                if (pos < LISTCAP) listB[pos] = key; else ovf = 1;
            }
        }
    }
    __syncthreads();  // B5

    // ---- p1 scan: per half, L owns 2 bins -> d1 (bits 19..10) ----
    {
        int c2[2];
        c2[0] = hist[half][L * 2]; c2[1] = hist[half][L * 2 + 1];
        const int pt = c2[0] + c2[1];
        int s = pt;
#pragma unroll
        for (int off = 1; off < 64; off <<= 1) {
            const int t = __shfl_down(s, off, 64);
            if (lane + off < 64) s += t;
        }
        if (lane == 0) waveTot[half][lwv] = s;
        __syncthreads();  // B6
        int U = s - pt;
#pragma unroll
        for (int w = 0; w < 8; ++w) if (w > lwv) U += waveTot[half][w];
        const int kkH = half ? kkB : kkA;
        int suf = 0;
#pragma unroll
        for (int k = 1; k >= 0; --k) {
            suf += c2[k];
            const int incl = U + suf;
            const int gg = incl - c2[k];
            if (gg < kkH && kkH <= incl) { bc_d[half] = L * 2 + k; bc_kk[half] = kkH - gg; }
        }
        __syncthreads();  // B7
    }
    const unsigned int pfx21A = (d0A << 10) | (unsigned int)bc_d[0];
    const unsigned int pfx21B = (d0B << 10) | (unsigned int)bc_d[1];
    kkA = bc_kk[0]; kkB = bc_kk[1];
    const int useFb = ovf;
    const int nA = (listCnt[0] < LISTCAP) ? listCnt[0] : LISTCAP;
    const int nB = (listCnt[1] < LISTCAP) ? listCnt[1] : LISTCAP;
    if (tid < 64) { hist[0][tid] = 0; hist[1][tid] = 0; }
    __syncthreads();  // B8

    // ---- p2: bits 9..4 (64 bins) from lists (or exact fallback) ----
    if (!useFb) {
        for (int q = tid; q < nA; q += 1024) {
            const unsigned int key = listA[q];
            if ((key >> 10) == pfx21A) atomicAdd(&hist[0][(key >> 4) & 63], 1);
        }
        for (int q = tid; q < nB; q += 1024) {
            const unsigned int key = listB[q];
            if ((key >> 10) == pfx21B) atomicAdd(&hist[1][(key >> 4) & 63], 1);
        }
    } else {
#pragma unroll
        for (int q = 0; q < 16; ++q) {
            const unsigned int key = KEY32(vrA[q]);
            if ((key >> 10) == pfx21A) atomicAdd(&hist[0][(key >> 4) & 63], 1);
        }
#pragma unroll
        for (int i = 0; i < 4; ++i) {
            const float4 vv = vldsB[i * 1024 + tid];
            const float vj[4] = {vv.x, vv.y, vv.z, vv.w};
#pragma unroll
            for (int j = 0; j < 4; ++j) {
                const unsigned int key = KEY32(vj[j]);
                if ((key >> 10) == pfx21B) atomicAdd(&hist[1][(key >> 4) & 63], 1);
            }
        }
    }
    __syncthreads();  // B9

    // ---- p2 scan: wave 0 = token A, wave 8 = token B (U = 0 within bin) ----
    if (wv == 0 || wv == 8) {
        const int h = wv >> 3;
        const int cnt = hist[h][lane];
        int s = cnt;
#pragma unroll
        for (int off = 1; off < 64; off <<= 1) {
            const int t = __shfl_down(s, off, 64);
            if (lane + off < 64) s += t;
        }
        const int kkH = h ? kkB : kkA;
        const int incl = s;
        const int gg = incl - cnt;
        if (gg < kkH && kkH <= incl) { bc_d[h] = lane; bc_kk[h] = kkH - gg; }
    }
    __syncthreads();  // B10
    const unsigned int pfx27A = (pfx21A << 6) | (unsigned int)bc_d[0];
    const unsigned int pfx27B = (pfx21B << 6) | (unsigned int)bc_d[1];
    kkA = bc_kk[0]; kkB = bc_kk[1];
    if (tid < 16) { hist[0][tid] = 0; hist[1][tid] = 0; }
    __syncthreads();  // B11

    // ---- p3: bits 3..0 (16 bins) from lists (or exact fallback) ----
    if (!useFb) {
        for (int q = tid; q < nA; q += 1024) {
            const unsigned int key = listA[q];
            if ((key >> 4) == pfx27A) atomicAdd(&hist[0][key & 15], 1);
        }
        for (int q = tid; q < nB; q += 1024) {
            const unsigned int key = listB[q];
            if ((key >> 4) == pfx27B) atomicAdd(&hist[1][key & 15], 1);
        }
    } else {
#pragma unroll
        for (int q = 0; q < 16; ++q) {
            const unsigned int key = KEY32(vrA[q]);
            if ((key >> 4) == pfx27A) atomicAdd(&hist[0][key & 15], 1);
        }
#pragma unroll
        for (int i = 0; i < 4; ++i) {
            const float4 vv = vldsB[i * 1024 + tid];
            const float vj[4] = {vv.x, vv.y, vv.z, vv.w};
#pragma unroll
            for (int j = 0; j < 4; ++j) {
                const unsigned int key = KEY32(vj[j]);
                if ((key >> 4) == pfx27B) atomicAdd(&hist[1][key & 15], 1);
            }
        }
    }
    __syncthreads();  // B12

    // ---- p3 scan: wave 0/8, lanes 0..15 ----
    if ((wv == 0 || wv == 8) && lane < 16) {
        const int h = wv >> 3;
        const int cnt = hist[h][lane];
        int s = cnt;
#pragma unroll
        for (int off = 1; off < 16; off <<= 1) {
            const int t = __shfl_down(s, off, 64);
            if (lane + off < 16) s += t;
        }
        const int kkH = h ? kkB : kkA;
        const int incl = s;
        const int gg = incl - cnt;
        if (gg < kkH && kkH <= incl) { bc_d[h] = lane; bc_kk[h] = kkH - gg; bc_eq[h] = cnt; }
    }
    __syncthreads();  // B13

    const unsigned int TA = (pfx27A << 4) | (unsigned int)bc_d[0];
    const unsigned int TB = (pfx27B << 4) | (unsigned int)bc_d[1];
    const int dropA = bc_eq[0] - bc_kk[0];
    const int dropB = bc_eq[1] - bc_kk[1];
    float* outpA = out + (size_t)tokA * PD;
    float* outpB = out + (size_t)tokB * PD;
    int* scanb = &hist[0][0];   // 1024-entry scan buffer for the rare tie path

    // ---- token A write (values from registers) ----
    if (dropA == 0) {
#pragma unroll
        for (int i = 0; i < 4; ++i) {
            nt4 o;
#pragma unroll
            for (int j = 0; j < 4; ++j) {
                const float val = vrA[i * 4 + j];
                const unsigned int key = KEY32(val);
                float res = (key >= TA) ? val : 0.0f;
                if (HEDGED(key, val, TA)) res = __fmul_rn(val, 0.5f);
                o[j] = res;
            }
            __builtin_nontemporal_store(o, (nt4*)(outpA + i * 4096 + tid * 4));
        }
    } else {
        if (tid == 0) baseCnt = 0;
        __syncthreads();
#pragma unroll
        for (int i = 0; i < 4; ++i) {
            int eqf[4], gtf[4];
            int myCnt = 0;
#pragma unroll
            for (int j = 0; j < 4; ++j) {
                const unsigned int key = KEY32(vrA[i * 4 + j]);
                eqf[j] = (key == TA); gtf[j] = (key > TA); myCnt += eqf[j];
            }
            scanb[tid] = myCnt;
            __syncthreads();
#pragma unroll 1
            for (int off = 1; off < 1024; off <<= 1) {
                const int t2 = (tid >= off) ? scanb[tid - off] : 0;
                __syncthreads();
                scanb[tid] += t2;
                __syncthreads();
            }
            int base = baseCnt + scanb[tid] - myCnt;
            nt4 o;
#pragma unroll
            for (int j = 0; j < 4; ++j) {
                const float val = vrA[i * 4 + j];
                const unsigned int key = KEY32(val);
                float res = 0.0f;
                if (gtf[j]) res = val;
                else if (eqf[j]) { if (base >= dropA) res = val; base++; }
                if (HEDGED(key, val, TA)) res = __fmul_rn(val, 0.5f);
                o[j] = res;
            }
            __builtin_nontemporal_store(o, (nt4*)(outpA + i * 4096 + tid * 4));
            __syncthreads();
            if (tid == 0) baseCnt += scanb[1023];
            __syncthreads();
        }
    }

    // ---- token B write (values from LDS) ----
    if (dropB == 0) {
#pragma unroll
        for (int i = 0; i < 4; ++i) {
            const float4 vv = vldsB[i * 1024 + tid];
            const float vj[4] = {vv.x, vv.y, vv.z, vv.w};
            nt4 o;
#pragma unroll
            for (int j = 0; j < 4; ++j) {
                const float val = vj[j];
                const unsigned int key = KEY32(val);
                float res = (key >= TB) ? val : 0.0f;
                if (HEDGED(key, val, TB)) res = __fmul_rn(val, 0.5f);
                o[j] = res;
            }
            __builtin_nontemporal_store(o, (nt4*)(outpB + i * 4096 + tid * 4));
        }
    } else {
        if (tid == 0) baseCnt = 0;
        __syncthreads();
#pragma unroll
        for (int i = 0; i < 4; ++i) {
            const float4 vv = vldsB[i * 1024 + tid];
            const float vj[4] = {vv.x, vv.y, vv.z, vv.w};
            int eqf[4], gtf[4];
            int myCnt = 0;
#pragma unroll
            for (int j = 0; j < 4; ++j) {
                const unsigned int key = KEY32(vj[j]);
                eqf[j] = (key == TB); gtf[j] = (key > TB); myCnt += eqf[j];
            }
            scanb[tid] = myCnt;
            __syncthreads();
#pragma unroll 1
            for (int off = 1; off < 1024; off <<= 1) {
                const int t2 = (tid >= off) ? scanb[tid - off] : 0;
                __syncthreads();
                scanb[tid] += t2;
                __syncthreads();
            }
            int base = baseCnt + scanb[tid] - myCnt;
            nt4 o;
#pragma unroll
            for (int j = 0; j < 4; ++j) {
                const float val = vj[j];
                const unsigned int key = KEY32(val);
                float res = 0.0f;
                if (gtf[j]) res = val;
                else if (eqf[j]) { if (base >= dropB) res = val; base++; }
                if (HEDGED(key, val, TB)) res = __fmul_rn(val, 0.5f);
                o[j] = res;
            }
            __builtin_nontemporal_store(o, (nt4*)(outpB + i * 4096 + tid * 4));
            __syncthreads();
            if (tid == 0) baseCnt += scanb[1023];
            __syncthreads();
        }
    }
}

// ---------------------------------------------------------------------------
// Kernel 2: deterministic reduction (f64 accum of f32 per-token metrics)
// ---------------------------------------------------------------------------
__global__ __launch_bounds__(256) void metrics_kernel(
    const float* __restrict__ wsm, float* __restrict__ out)
{
    __shared__ double red[256];
    const int tid = threadIdx.x;
    double sums[10];
#pragma unroll
    for (int q = 0; q < 10; ++q) sums[q] = 0.0;
    for (int t = tid; t < NTOK; t += 256) {
#pragma unroll
        for (int q = 0; q < 10; ++q) sums[q] += (double)wsm[t * 10 + q];
    }
    double tot[10];
    for (int q = 0; q < 10; ++q) {
        red[tid] = sums[q];
        __syncthreads();
        for (int off = 128; off > 0; off >>= 1) {
            if (tid < off) red[tid] += red[tid + off];
            __syncthreads();
        }
        tot[q] = red[0];
        __syncthreads();
    }
    if (tid == 0) {
        const double inv = 1.0 / (double)NTOK;
        double mp[8];
        double mm = 0.0;
#pragma unroll
        for (int c = 0; c < 8; ++c) { mp[c] = tot[c] * inv; mm += mp[c]; }
        mm *= 0.125;
        double var = 0.0;
#pragma unroll
        for (int c = 0; c < 8; ++c) { const double d = mp[c] - mm; var += d * d; }
        var *= 0.125;
        out[(size_t)NTOK * PD + 0] = (float)(tot[9] * inv);  // entropy
        out[(size_t)NTOK * PD + 1] = (float)(tot[8] * inv);  // intensity mean
        out[(size_t)NTOK * PD + 2] = (float)sqrt(var);       // diversity
    }
}

extern "C" void kernel_launch(void* const* d_in, const int* in_sizes, int n_in,
                              void* d_out, int out_size, void* d_ws, size_t ws_size,
                              hipStream_t stream) {
    (void)in_sizes; (void)n_in; (void)out_size; (void)ws_size;
    const float* x   = (const float*)d_in[0];
    const float* pat = (const float*)d_in[1];
    const float* Wp  = (const float*)d_in[2];
    const float* bp  = (const float*)d_in[3];
    const float* Wi  = (const float*)d_in[4];
    const float* bi  = (const float*)d_in[5];
    float* out = (float*)d_out;
    float* wsm = (float*)d_ws;   // 4096 tokens * 10 floats = 160 KB

    hipLaunchKernelGGL(logits_kernel, dim3(NTOK / 4), dim3(256), 0, stream,
                       x, Wp, bp, Wi, bi, wsm);
    hipLaunchKernelGGL(flow_kernel, dim3(NTOK / 2), dim3(1024), 0, stream,
                       pat, wsm, out);
    hipLaunchKernelGGL(metrics_kernel, dim3(1), dim3(256), 0, stream, wsm, out);
}

// Round 15
// 134.736 us; speedup vs baseline: 1.2426x; 1.2426x over previous
//
#include <hip/hip_runtime.h>
#include <math.h>

#define NTOK 4096
#define INDIM 128
#define PD 16384      // D = OUT*IN
#define NPAT 8
#define KSEL 1638     // int(16384*0.1)
#define HEDGE_ULP 8
#define HEDGE_CUT 0.066f
#define LISTCAP 2048

typedef float nt4 __attribute__((ext_vector_type(4)));  // native vec for NT stores

#define KEY32(f) (__float_as_uint(f) & 0x7fffffffu)
#define HEDGED(key, val, T) \
    ((((key) >= (T) ? (key) - (T) : (T) - (key)) <= (unsigned int)HEDGE_ULP) \
     && (fabsf(val) < HEDGE_CUT))

// ---------------------------------------------------------------------------
// Kernel 0: logits + softmax + sigmoid per token (validated arithmetic).
// ---------------------------------------------------------------------------
__global__ __launch_bounds__(256) void logits_kernel(
    const float* __restrict__ x,
    const float* __restrict__ Wp,
    const float* __restrict__ bp,
    const float* __restrict__ Wi,
    const float* __restrict__ bi,
    float* __restrict__ wsm)
{
    const int tid = threadIdx.x;
    const int lane = tid & 63;
    const int wv = tid >> 6;
    const int token = blockIdx.x * 4 + wv;

    float acc = 0.0f;
    if (lane < 9) {
        const float* xrow = x + (size_t)token * INDIM;
        if (lane < 8) {
            for (int l = 0; l < INDIM; ++l)
                acc = __fmaf_rn(xrow[l], Wp[l * NPAT + lane], acc);
            acc = __fadd_rn(acc, bp[lane]);
        } else {
            for (int l = 0; l < INDIM; ++l)
                acc = __fmaf_rn(xrow[l], Wi[l], acc);
            acc = __fadd_rn(acc, bi[0]);
        }
    }
    float d[9];
#pragma unroll
    for (int c = 0; c < 9; ++c) d[c] = __shfl(acc, c, 64);

    if (lane == 0) {
        float m = d[0];
#pragma unroll
        for (int c = 1; c < 8; ++c) m = fmaxf(m, d[c]);
        float ee[8];
#pragma unroll
        for (int c = 0; c < 8; ++c)
            ee[c] = (float)exp((double)__fsub_rn(d[c], m));
        const float ssum = __fadd_rn(
            __fadd_rn(__fadd_rn(ee[0], ee[1]), __fadd_rn(ee[2], ee[3])),
            __fadd_rn(__fadd_rn(ee[4], ee[5]), __fadd_rn(ee[6], ee[7])));
        double ent = 0.0;
        float* wrow = wsm + (size_t)token * 10;
#pragma unroll
        for (int c = 0; c < 8; ++c) {
            const float p = __fdiv_rn(ee[c], ssum);
            wrow[c] = p;
            ent -= (double)p * log((double)p + 1e-8);
        }
        const float z = d[8];
        const float einv = (float)exp(-(double)z);
        const float it = __fdiv_rn(1.0f, __fadd_rn(1.0f, einv));
        wrow[8] = it;
        wrow[9] = (float)ent;
    }
}

// ---------------------------------------------------------------------------
// Kernel 1: one 512-thread block per token. Values split: groups 0..3 (16/thr)
// in REGISTERS, groups 4..7 in LDS (32 KB) -> ~48 KB/block, 3 blocks/CU.
//  mixture : validated numpy-order f32; pass-0 (bits 30..20) fused
//  select  : 11+10+6+4-bit radix. Pass 1 = regs + one 32KB LDS scan, pushing
//            d0-matches to a compact LDS list; passes 2/3 run off the list
//            (64/16 bins, wave-0 scans). ovf -> exact full-rescan fallback.
//  write   : regs/LDS + hedged nontemporal stores
// ---------------------------------------------------------------------------
__global__ __launch_bounds__(512) void flow_kernel(
    const float* __restrict__ pat,
    const float* __restrict__ wsm,
    float* __restrict__ out)
{
    __shared__ float4 vlds4[2048];       // 32 KB: groups 4..7
    __shared__ int hist[2048];           // 8 KB: p0 bins / p1 / p2 / p3 / tie-scan
    __shared__ unsigned int list[LISTCAP]; // 8 KB: d0-matching keys
    __shared__ int listCnt;
    __shared__ int waveTot[8];
    __shared__ int bc_d, bc_kk, bc_eq;
    __shared__ int ovf;
    __shared__ int baseCnt;

    const int tid  = threadIdx.x;
    const int wv   = tid >> 6;
    const int lane = tid & 63;
    const int token = blockIdx.x;

    // ---- zero histogram & flags; must complete before fused atomics ----
    hist[tid] = 0; hist[tid + 512] = 0; hist[tid + 1024] = 0; hist[tid + 1536] = 0;
    if (tid == 0) { ovf = 0; listCnt = 0; }
    __syncthreads();  // B0

    const float* wrow = wsm + (size_t)token * 10;
    float pwr[8];
#pragma unroll
    for (int c = 0; c < 8; ++c) pwr[c] = wrow[c];
    const float inten = wrow[8];

    // ---- mixture (validated) with fused pass-0 histogram (bits 30..20) ----
    float vr[16];                        // groups 0..3 stay in registers
#pragma unroll
    for (int i = 0; i < 8; ++i) {
        const int e = i * 2048 + tid * 4;
        float4 ap = *(const float4*)(pat + e);
        float r0 = __fmul_rn(pwr[0], ap.x);
        float r1 = __fmul_rn(pwr[0], ap.y);
        float r2 = __fmul_rn(pwr[0], ap.z);
        float r3 = __fmul_rn(pwr[0], ap.w);
#pragma unroll
        for (int p = 1; p < NPAT; ++p) {
            ap = *(const float4*)(pat + (size_t)p * PD + e);
            r0 = __fadd_rn(r0, __fmul_rn(pwr[p], ap.x));
            r1 = __fadd_rn(r1, __fmul_rn(pwr[p], ap.y));
            r2 = __fadd_rn(r2, __fmul_rn(pwr[p], ap.z));
            r3 = __fadd_rn(r3, __fmul_rn(pwr[p], ap.w));
        }
        float4 o;
        o.x = __fmul_rn(r0, inten);
        o.y = __fmul_rn(r1, inten);
        o.z = __fmul_rn(r2, inten);
        o.w = __fmul_rn(r3, inten);
        if (i < 4) {
            vr[i * 4 + 0] = o.x; vr[i * 4 + 1] = o.y;
            vr[i * 4 + 2] = o.z; vr[i * 4 + 3] = o.w;
        } else {
            vlds4[(i - 4) * 512 + tid] = o;
        }
        atomicAdd(&hist[KEY32(o.x) >> 20], 1);
        atomicAdd(&hist[KEY32(o.y) >> 20], 1);
        atomicAdd(&hist[KEY32(o.z) >> 20], 1);
        atomicAdd(&hist[KEY32(o.w) >> 20], 1);
    }
    __syncthreads();  // B1: values ready, p0 hist complete

    // ---- p0 scan: 2048 bins (thread owns 4) -> d0 (bits 30..20) ----
    int kk = KSEL;
    {
        int c4[4];
#pragma unroll
        for (int k = 0; k < 4; ++k) c4[k] = hist[tid * 4 + k];
        const int pt = c4[0] + c4[1] + c4[2] + c4[3];
        int s = pt;
#pragma unroll
        for (int off = 1; off < 64; off <<= 1) {
            const int t = __shfl_down(s, off, 64);
            if (lane + off < 64) s += t;
        }
        if (lane == 0) waveTot[wv] = s;
        __syncthreads();  // B2
        int U = s - pt;
#pragma unroll
        for (int w = 0; w < 8; ++w) if (w > wv) U += waveTot[w];
        int suf = 0;
#pragma unroll
        for (int k = 3; k >= 0; --k) {
            suf += c4[k];
            const int incl = U + suf;
            const int gg = incl - c4[k];
            if (gg < kk && kk <= incl) { bc_d = tid * 4 + k; bc_kk = kk - gg; }
        }
        __syncthreads();  // B3
    }
    const unsigned int d0 = (unsigned int)bc_d;
    kk = bc_kk;
    hist[tid] = 0; hist[tid + 512] = 0;   // rezero 1024 bins for p1
    __syncthreads();  // B4

    // ---- p1: regs + one LDS scan; hist bits 19..10; push d0-matches ----
#pragma unroll
    for (int q = 0; q < 16; ++q) {
        const unsigned int key = KEY32(vr[q]);
        if ((key >> 20) == d0) {
            atomicAdd(&hist[(key >> 10) & 1023], 1);
            const int pos = atomicAdd(&listCnt, 1);
            if (pos < LISTCAP) list[pos] = key; else ovf = 1;
        }
    }
#pragma unroll
    for (int i = 0; i < 4; ++i) {
        const float4 vv = vlds4[i * 512 + tid];
        const float vj[4] = {vv.x, vv.y, vv.z, vv.w};
#pragma unroll
        for (int j = 0; j < 4; ++j) {
            const unsigned int key = KEY32(vj[j]);
            if ((key >> 20) == d0) {
                atomicAdd(&hist[(key >> 10) & 1023], 1);
                const int pos = atomicAdd(&listCnt, 1);
                if (pos < LISTCAP) list[pos] = key; else ovf = 1;
            }
        }
    }
    __syncthreads();  // B5

    // ---- p1 scan: 1024 bins (thread owns 2) -> d1 (bits 19..10) ----
    {
        int c2[2];
        c2[0] = hist[tid * 2]; c2[1] = hist[tid * 2 + 1];
        const int pt = c2[0] + c2[1];
        int s = pt;
#pragma unroll
        for (int off = 1; off < 64; off <<= 1) {
            const int t = __shfl_down(s, off, 64);
            if (lane + off < 64) s += t;
        }
        if (lane == 0) waveTot[wv] = s;
        __syncthreads();  // B6
        int U = s - pt;
#pragma unroll
        for (int w = 0; w < 8; ++w) if (w > wv) U += waveTot[w];
        int suf = 0;
#pragma unroll
        for (int k = 1; k >= 0; --k) {
            suf += c2[k];
            const int incl = U + suf;
            const int gg = incl - c2[k];
            if (gg < kk && kk <= incl) { bc_d = tid * 2 + k; bc_kk = kk - gg; }
        }
        __syncthreads();  // B7
    }
    const unsigned int pfx21 = (d0 << 10) | (unsigned int)bc_d;
    kk = bc_kk;
    const int useFb = ovf;
    const int nlist = (listCnt < LISTCAP) ? listCnt : LISTCAP;
    if (tid < 64) hist[tid] = 0;          // 64 bins for p2
    __syncthreads();  // B8

    // ---- p2: bits 9..4 (64 bins) from the list (or exact fallback) ----
    if (!useFb) {
        for (int q = tid; q < nlist; q += 512) {
            const unsigned int key = list[q];
            if ((key >> 10) == pfx21) atomicAdd(&hist[(key >> 4) & 63], 1);
        }
    } else {
#pragma unroll
        for (int q = 0; q < 16; ++q) {
            const unsigned int key = KEY32(vr[q]);
            if ((key >> 10) == pfx21) atomicAdd(&hist[(key >> 4) & 63], 1);
        }
#pragma unroll
        for (int i = 0; i < 4; ++i) {
            const float4 vv = vlds4[i * 512 + tid];
            const float vj[4] = {vv.x, vv.y, vv.z, vv.w};
#pragma unroll
            for (int j = 0; j < 4; ++j) {
                const unsigned int key = KEY32(vj[j]);
                if ((key >> 10) == pfx21) atomicAdd(&hist[(key >> 4) & 63], 1);
            }
        }
    }
    __syncthreads();  // B9

    // ---- p2 scan: 64 bins, wave 0 only ----
    if (wv == 0) {
        const int cnt = hist[lane];
        int s = cnt;
#pragma unroll
        for (int off = 1; off < 64; off <<= 1) {
            const int t = __shfl_down(s, off, 64);
            if (lane + off < 64) s += t;
        }
        const int incl = s;               // sum over bins >= lane
        const int gg = incl - cnt;
        if (gg < kk && kk <= incl) { bc_d = lane; bc_kk = kk - gg; }
    }
    __syncthreads();  // B10
    const unsigned int pfx27 = (pfx21 << 6) | (unsigned int)bc_d;
    kk = bc_kk;
    if (tid < 16) hist[tid] = 0;          // 16 bins for p3
    __syncthreads();  // B11

    // ---- p3: bits 3..0 (16 bins) from the list (or exact fallback) ----
    if (!useFb) {
        for (int q = tid; q < nlist; q += 512) {
            const unsigned int key = list[q];
            if ((key >> 4) == pfx27) atomicAdd(&hist[key & 15], 1);
        }
    } else {
#pragma unroll
        for (int q = 0; q < 16; ++q) {
            const unsigned int key = KEY32(vr[q]);
            if ((key >> 4) == pfx27) atomicAdd(&hist[key & 15], 1);
        }
#pragma unroll
        for (int i = 0; i < 4; ++i) {
            const float4 vv = vlds4[i * 512 + tid];
            const float vj[4] = {vv.x, vv.y, vv.z, vv.w};
#pragma unroll
            for (int j = 0; j < 4; ++j) {
                const unsigned int key = KEY32(vj[j]);
                if ((key >> 4) == pfx27) atomicAdd(&hist[key & 15], 1);
            }
        }
    }
    __syncthreads();  // B12

    // ---- p3 scan: 16 bins, wave 0 lanes 0..15 ----
    if (wv == 0 && lane < 16) {
        const int cnt = hist[lane];
        int s = cnt;
#pragma unroll
        for (int off = 1; off < 16; off <<= 1) {
            const int t = __shfl_down(s, off, 64);
            if (lane + off < 16) s += t;
        }
        const int incl = s;
        const int gg = incl - cnt;
        if (gg < kk && kk <= incl) { bc_d = lane; bc_kk = kk - gg; bc_eq = cnt; }
    }
    __syncthreads();  // B13

    const unsigned int T = (pfx27 << 4) | (unsigned int)bc_d;
    const int dropLow = bc_eq - bc_kk;
    float* outp = out + (size_t)token * PD;

    if (dropLow == 0) {
        // common case: keep key >= T, hedge the boundary zone
#pragma unroll
        for (int i = 0; i < 8; ++i) {
            float vj[4];
            if (i < 4) {
                vj[0] = vr[i * 4 + 0]; vj[1] = vr[i * 4 + 1];
                vj[2] = vr[i * 4 + 2]; vj[3] = vr[i * 4 + 3];
            } else {
                const float4 vv = vlds4[(i - 4) * 512 + tid];
                vj[0] = vv.x; vj[1] = vv.y; vj[2] = vv.z; vj[3] = vv.w;
            }
            nt4 o;
#pragma unroll
            for (int j = 0; j < 4; ++j) {
                const float val = vj[j];
                const unsigned int key = KEY32(val);
                float res = (key >= T) ? val : 0.0f;
                if (HEDGED(key, val, T)) res = __fmul_rn(val, 0.5f);
                o[j] = res;
            }
            __builtin_nontemporal_store(o, (nt4*)(outp + i * 2048 + tid * 4));
        }
    } else {
        // exact f32 ties straddling the boundary: drop the dropLow LOWEST
        // indices; hedging overrides small-|v| cases. hist = scan buffer.
        if (tid == 0) baseCnt = 0;
        __syncthreads();
#pragma unroll
        for (int i = 0; i < 8; ++i) {
            float vj[4];
            if (i < 4) {
                vj[0] = vr[i * 4 + 0]; vj[1] = vr[i * 4 + 1];
                vj[2] = vr[i * 4 + 2]; vj[3] = vr[i * 4 + 3];
            } else {
                const float4 vv = vlds4[(i - 4) * 512 + tid];
                vj[0] = vv.x; vj[1] = vv.y; vj[2] = vv.z; vj[3] = vv.w;
            }
            int eqf[4], gtf[4];
            int myCnt = 0;
#pragma unroll
            for (int j = 0; j < 4; ++j) {
                const unsigned int key = KEY32(vj[j]);
                eqf[j] = (key == T);
                gtf[j] = (key > T);
                myCnt += eqf[j];
            }
            hist[tid] = myCnt;
            __syncthreads();
#pragma unroll 1
            for (int off = 1; off < 512; off <<= 1) {
                const int t2 = (tid >= off) ? hist[tid - off] : 0;
                __syncthreads();
                hist[tid] += t2;
                __syncthreads();
            }
            int base = baseCnt + hist[tid] - myCnt;  // ties with smaller index
            nt4 o;
#pragma unroll
            for (int j = 0; j < 4; ++j) {
                const float val = vj[j];
                const unsigned int key = KEY32(val);
                float res = 0.0f;
                if (gtf[j]) res = val;
                else if (eqf[j]) { if (base >= dropLow) res = val; base++; }
                if (HEDGED(key, val, T)) res = __fmul_rn(val, 0.5f);
                o[j] = res;
            }
            __builtin_nontemporal_store(o, (nt4*)(outp + i * 2048 + tid * 4));
            __syncthreads();
            if (tid == 0) baseCnt += hist[511];
            __syncthreads();
        }
    }
}

// ---------------------------------------------------------------------------
// Kernel 2: deterministic reduction (f64 accum of f32 per-token metrics)
// ---------------------------------------------------------------------------
__global__ __launch_bounds__(256) void metrics_kernel(
    const float* __restrict__ wsm, float* __restrict__ out)
{
    __shared__ double red[256];
    const int tid = threadIdx.x;
    double sums[10];
#pragma unroll
    for (int q = 0; q < 10; ++q) sums[q] = 0.0;
    for (int t = tid; t < NTOK; t += 256) {
#pragma unroll
        for (int q = 0; q < 10; ++q) sums[q] += (double)wsm[t * 10 + q];
    }
    double tot[10];
    for (int q = 0; q < 10; ++q) {
        red[tid] = sums[q];
        __syncthreads();
        for (int off = 128; off > 0; off >>= 1) {
            if (tid < off) red[tid] += red[tid + off];
            __syncthreads();
        }
        tot[q] = red[0];
        __syncthreads();
    }
    if (tid == 0) {
        const double inv = 1.0 / (double)NTOK;
        double mp[8];
        double mm = 0.0;
#pragma unroll
        for (int c = 0; c < 8; ++c) { mp[c] = tot[c] * inv; mm += mp[c]; }
        mm *= 0.125;
        double var = 0.0;
#pragma unroll
        for (int c = 0; c < 8; ++c) { const double d = mp[c] - mm; var += d * d; }
        var *= 0.125;
        out[(size_t)NTOK * PD + 0] = (float)(tot[9] * inv);  // entropy
        out[(size_t)NTOK * PD + 1] = (float)(tot[8] * inv);  // intensity mean
        out[(size_t)NTOK * PD + 2] = (float)sqrt(var);       // diversity
    }
}

extern "C" void kernel_launch(void* const* d_in, const int* in_sizes, int n_in,
                              void* d_out, int out_size, void* d_ws, size_t ws_size,
                              hipStream_t stream) {
    (void)in_sizes; (void)n_in; (void)out_size; (void)ws_size;
    const float* x   = (const float*)d_in[0];
    const float* pat = (const float*)d_in[1];
    const float* Wp  = (const float*)d_in[2];
    const float* bp  = (const float*)d_in[3];
    const float* Wi  = (const float*)d_in[4];
    const float* bi  = (const float*)d_in[5];
    float* out = (float*)d_out;
    float* wsm = (float*)d_ws;   // 4096 tokens * 10 floats = 160 KB

    hipLaunchKernelGGL(logits_kernel, dim3(NTOK / 4), dim3(256), 0, stream,
                       x, Wp, bp, Wi, bi, wsm);
    hipLaunchKernelGGL(flow_kernel, dim3(NTOK), dim3(512), 0, stream,
                       pat, wsm, out);
    hipLaunchKernelGGL(metrics_kernel, dim3(1), dim3(256), 0, stream, wsm, out);
}